// Round 16
// baseline (1076.642 us; speedup 1.0000x reference)
//
#include <hip/hip_runtime.h>
#include <hip/hip_bf16.h>

#define NN 50000
#define NE 800000
#define NB 16
#define T_STEPS 12
#define SCAN_B 196  // ceil(NN/256)
#define EAW_BLOCKS 2048

typedef __attribute__((ext_vector_type(8))) short short8;
typedef __attribute__((ext_vector_type(4))) float f32x4;
typedef __attribute__((ext_vector_type(2))) float f32x2;
typedef unsigned short u16;
typedef unsigned int u32;

#if __has_builtin(__builtin_amdgcn_fdot2_f32_bf16)
#define HAS_DOT2_BF16 1
typedef __attribute__((ext_vector_type(2))) __bf16 bf16x2;
__device__ __forceinline__ bf16x2 as_bf16x2(u32 v) {
    union { u32 i; bf16x2 h; } u; u.i = v; return u.h;
}
#else
#define HAS_DOT2_BF16 0
#endif

__device__ __forceinline__ float bf2f(u32 u) {
    union { u32 i; float f; } v; v.i = u << 16; return v.f;
}
__device__ __forceinline__ u16 f2bf(float f) {
    union { float f; u32 i; } v; v.f = f;
    u32 r = v.i + 0x7fffu + ((v.i >> 16) & 1u);
    return (u16)(r >> 16);
}
__device__ __forceinline__ f32x4 mfma16(short8 a, short8 b, f32x4 c) {
    return __builtin_amdgcn_mfma_f32_16x16x32_bf16(a, b, c, 0, 0, 0);
}

// pack 2 floats -> fp8 e4m3 pair in low 16 bits (HW instruction; OCP on gfx950)
__device__ __forceinline__ u32 pk2_fp8(float o0, float o1) {
#if __has_builtin(__builtin_amdgcn_cvt_pk_fp8_f32)
    return (u32)__builtin_amdgcn_cvt_pk_fp8_f32(o0, o1, 0, false);
#else
    u32 a = 0;
    asm("v_cvt_pk_fp8_f32 %0, %1, %2" : "+v"(a) : "v"(o0), "v"(o1));
    return a;
#endif
}
__device__ __forceinline__ u32 pk4_fp8(float o0, float o1, float o2, float o3) {
    return (pk2_fp8(o0, o1) & 0xffffu) | (pk2_fp8(o2, o3) << 16);
}
__device__ __forceinline__ unsigned char f2fp8b(float v) {
    return (unsigned char)(pk2_fp8(v, 0.f) & 0xffu);
}

// decode 4x fp8 e4m3 from u32
__device__ __forceinline__ void fp8x4f(u32 w, float& f0, float& f1, float& f2, float& f3) {
#if __has_builtin(__builtin_amdgcn_cvt_pk_f32_fp8)
    f32x2 r0 = __builtin_amdgcn_cvt_pk_f32_fp8((int)w, false);
    f32x2 r1 = __builtin_amdgcn_cvt_pk_f32_fp8((int)w, true);
    f0 = r0[0]; f1 = r0[1]; f2 = r1[0]; f3 = r1[1];
#else
    f32x2 r0, r1;
    u32 hi = w >> 16;
    asm("v_cvt_pk_f32_fp8 %0, %1" : "=v"(r0) : "v"(w));
    asm("v_cvt_pk_f32_fp8 %0, %1" : "=v"(r1) : "v"(hi));
    f0 = r0[0]; f1 = r0[1]; f2 = r1[0]; f3 = r1[1];
#endif
}

// packed weight layout (bf16): elem(((ks*8+nt)*64+l)*8+j) = W[ks*32+((l>>4))*8+j][nt*16+(l&15)]
#define W1OFF 0
#define W2OFF 32768
#define WSOFF 49152
#define ENCOFF 65536
#define PACKN 73728

// ---------------- setup kernels ----------------

__global__ void k_hist(const int* __restrict__ dst, int* __restrict__ hist) {
    int e = blockIdx.x * 256 + threadIdx.x;
    if (e < NE) atomicAdd(&hist[dst[e]], 1);
}

__global__ void k_scanA(const int* __restrict__ hist, int* __restrict__ excl,
                        int* __restrict__ bsum) {
    __shared__ int sh[256];
    int t = threadIdx.x, b = blockIdx.x;
    int idx = b * 256 + t;
    int v = (idx < NN) ? hist[idx] : 0;
    sh[t] = v;
    __syncthreads();
    for (int off = 1; off < 256; off <<= 1) {
        int add = (t >= off) ? sh[t - off] : 0;
        __syncthreads();
        sh[t] += add;
        __syncthreads();
    }
    if (idx < NN) excl[idx] = sh[t] - v;
    if (t == 255) bsum[b] = sh[255];
}

__global__ void k_scanB(int* __restrict__ bsum) {
    __shared__ int sh[256];
    int t = threadIdx.x;
    int v = (t < SCAN_B) ? bsum[t] : 0;
    sh[t] = v;
    __syncthreads();
    for (int off = 1; off < 256; off <<= 1) {
        int add = (t >= off) ? sh[t - off] : 0;
        __syncthreads();
        sh[t] += add;
        __syncthreads();
    }
    if (t < SCAN_B) bsum[t] = sh[t] - v;  // exclusive
}

__global__ void k_scanC(const int* __restrict__ excl, const int* __restrict__ bsum,
                        int* __restrict__ rowptr, int* __restrict__ cursor) {
    int idx = blockIdx.x * 256 + threadIdx.x;
    if (idx < NN) {
        int r = excl[idx] + bsum[blockIdx.x];
        rowptr[idx] = r;
        cursor[idx] = r;
    }
    if (idx == 0) rowptr[NN] = NE;
}

// scatter (src id + bf16 edge-attr) into CSR order; atomic-latency-bound, stores ~free.
__global__ void k_scatter(const int* __restrict__ src, const int* __restrict__ dst,
                          const float* __restrict__ eattr, int* __restrict__ cursor,
                          int* __restrict__ ssrc, u16* __restrict__ ea8) {
    int e = blockIdx.x * 256 + threadIdx.x;
    if (e >= NE) return;
    int d = dst[e];
    int pos = atomicAdd(&cursor[d], 1);
    ssrc[pos] = src[e];
    const float* ap = eattr + (size_t)e * 8;
    uint4 w;
    w.x = (u32)f2bf(ap[0]) | ((u32)f2bf(ap[1]) << 16);
    w.y = (u32)f2bf(ap[2]) | ((u32)f2bf(ap[3]) << 16);
    w.z = (u32)f2bf(ap[4]) | ((u32)f2bf(ap[5]) << 16);
    w.w = (u32)f2bf(ap[6]) | ((u32)f2bf(ap[7]) << 16);
    *(uint4*)(ea8 + (size_t)pos * 8) = w;
}

// eaw[p][c] = fp8( sum_k ea8[p][k] * msg_w[128+k][c] ) — fully coalesced stream.
// dot2-bf16 path: ea8 words ARE bf16 pairs; weights pre-packed as bf16 pairs (32 VGPR).
__global__ __launch_bounds__(256) void k_eaw(
    const u16* __restrict__ ea8, const float* __restrict__ msg_w,
    unsigned char* __restrict__ eaw) {
    const int tid = threadIdx.x;
    const int hex = tid & 15;   // channel slice [hex*8, hex*8+8)
    const int esub = tid >> 4;  // 0..15
#if HAS_DOT2_BF16
    u32 wp[4][8];
#pragma unroll
    for (int kk = 0; kk < 4; ++kk) {
#pragma unroll
        for (int c = 0; c < 8; ++c) {
            float w0 = msg_w[(size_t)(128 + 2 * kk) * 128 + hex * 8 + c];
            float w1 = msg_w[(size_t)(128 + 2 * kk + 1) * 128 + hex * 8 + c];
            wp[kk][c] = (u32)f2bf(w0) | ((u32)f2bf(w1) << 16);
        }
    }
#else
    float w[8][8];
#pragma unroll
    for (int k = 0; k < 8; ++k) {
        float4 v0 = *(const float4*)(msg_w + (size_t)(128 + k) * 128 + hex * 8);
        float4 v1 = *(const float4*)(msg_w + (size_t)(128 + k) * 128 + hex * 8 + 4);
        w[k][0] = v0.x; w[k][1] = v0.y; w[k][2] = v0.z; w[k][3] = v0.w;
        w[k][4] = v1.x; w[k][5] = v1.y; w[k][6] = v1.z; w[k][7] = v1.w;
    }
#endif
    int p = blockIdx.x * 16 + esub;
    if (p >= NE) return;
    uint4 ev = *(const uint4*)(ea8 + (size_t)p * 8);
    while (true) {
        int pn = p + EAW_BLOCKS * 16;
        bool more = pn < NE;
        uint4 evn;
        if (more) evn = *(const uint4*)(ea8 + (size_t)pn * 8);
        float o[8];
#if HAS_DOT2_BF16
        u32 ep[4] = {ev.x, ev.y, ev.z, ev.w};
#pragma unroll
        for (int c = 0; c < 8; ++c) o[c] = 0.f;
#pragma unroll
        for (int kk = 0; kk < 4; ++kk) {
            bf16x2 ea2 = as_bf16x2(ep[kk]);
#pragma unroll
            for (int c = 0; c < 8; ++c)
                o[c] = __builtin_amdgcn_fdot2_f32_bf16(ea2, as_bf16x2(wp[kk][c]), o[c], false);
        }
#else
        float ef[8];
        ef[0] = bf2f(ev.x & 0xffffu); ef[1] = bf2f(ev.x >> 16);
        ef[2] = bf2f(ev.y & 0xffffu); ef[3] = bf2f(ev.y >> 16);
        ef[4] = bf2f(ev.z & 0xffffu); ef[5] = bf2f(ev.z >> 16);
        ef[6] = bf2f(ev.w & 0xffffu); ef[7] = bf2f(ev.w >> 16);
#pragma unroll
        for (int c = 0; c < 8; ++c) o[c] = ef[0] * w[0][c];
#pragma unroll
        for (int k = 1; k < 8; ++k)
#pragma unroll
            for (int c = 0; c < 8; ++c) o[c] += ef[k] * w[k][c];
#endif
        uint2 q;
        q.x = pk4_fp8(o[0], o[1], o[2], o[3]);
        q.y = pk4_fp8(o[4], o[5], o[6], o[7]);
        *(uint2*)(eaw + (size_t)p * 128 + hex * 8) = q;
        if (!more) break;
        p = pn;
        ev = evn;
    }
}

__global__ void k_pack(const float* __restrict__ up_w1, const float* __restrict__ up_w2,
                       const float* __restrict__ msg_w, const float* __restrict__ enc_w,
                       u16* __restrict__ packed) {
    int idx = blockIdx.x * 256 + threadIdx.x;
    if (idx >= PACKN) return;
    const float* srcp; int local;
    if (idx < W2OFF)        { srcp = up_w1; local = idx; }
    else if (idx < WSOFF)   { srcp = up_w2; local = idx - W2OFF; }
    else if (idx < ENCOFF)  { srcp = msg_w; local = idx - WSOFF; }   // rows 0..127 (state part)
    else                    { srcp = enc_w; local = idx - ENCOFF; }
    int j = local & 7;
    int l = (local >> 3) & 63;
    int ntks = local >> 9;
    int nt = ntks & 7;
    int ks = ntks >> 3;
    int krow = ks * 32 + (l >> 4) * 8 + j;
    int col = nt * 16 + (l & 15);
    packed[idx] = f2bf(srcp[krow * 128 + col]);
}

// ---------------- encoder: state_h = bf16(relu(x@enc_w+enc_b)); swf8 = fp8(state@Ws+msg_b) ----------------

__global__ __launch_bounds__(256) void k_encode(
    const float* __restrict__ x, const float* __restrict__ enc_b,
    const float* __restrict__ msg_b, const u16* __restrict__ packed,
    u16* __restrict__ state_h, unsigned char* __restrict__ swf8) {
    __shared__ u16 stage[4][2048];
    const int wv = threadIdx.x >> 6, l = threadIdx.x & 63;
    const int lr = l & 15, kb = l >> 4;
    const int rb = blockIdx.x * 64 + wv * 16;
    const int row = rb + lr;
    const int rowc = row < NN ? row : NN - 1;

    f32x4 acc[8] = {};
#pragma unroll
    for (int ks = 0; ks < 2; ++ks) {
        const float* ap = x + (size_t)rowc * 64 + ks * 32 + kb * 8;
        float4 a0 = *(const float4*)ap;
        float4 a1 = *(const float4*)(ap + 4);
        short8 a;
        a[0] = (short)f2bf(a0.x); a[1] = (short)f2bf(a0.y);
        a[2] = (short)f2bf(a0.z); a[3] = (short)f2bf(a0.w);
        a[4] = (short)f2bf(a1.x); a[5] = (short)f2bf(a1.y);
        a[6] = (short)f2bf(a1.z); a[7] = (short)f2bf(a1.w);
        const u16* bp = packed + ENCOFF + (size_t)(ks * 512 + l) * 8;
#pragma unroll
        for (int nt = 0; nt < 8; ++nt) {
            short8 b = *(const short8*)(bp + nt * 512);
            acc[nt] = mfma16(a, b, acc[nt]);
        }
    }
#pragma unroll
    for (int nt = 0; nt < 8; ++nt) {
        int col = nt * 16 + lr;
        float bias = enc_b[col];
#pragma unroll
        for (int j = 0; j < 4; ++j) {
            int rl = kb * 4 + j;
            int r = rb + rl;
            float v = acc[nt][j] + bias;
            v = v > 0.f ? v : 0.f;
            u16 h = f2bf(v);
            if (r < NN) state_h[(size_t)r * 128 + col] = h;
            int byte = (rl * 256 + col * 2) ^ ((rl & 7) << 4);
            *(u16*)((char*)stage[wv] + byte) = h;
        }
    }
    f32x4 acc3[8] = {};
#pragma unroll
    for (int ks = 0; ks < 4; ++ks) {
        int byte = (lr * 256 + ks * 64 + kb * 16) ^ ((lr & 7) << 4);
        short8 a = *(const short8*)((char*)stage[wv] + byte);
        const u16* bp = packed + WSOFF + (size_t)(ks * 512 + l) * 8;
#pragma unroll
        for (int nt = 0; nt < 8; ++nt) {
            short8 b = *(const short8*)(bp + nt * 512);
            acc3[nt] = mfma16(a, b, acc3[nt]);
        }
    }
#pragma unroll
    for (int nt = 0; nt < 8; ++nt) {
        int col = nt * 16 + lr;
        float bias = msg_b[col];
#pragma unroll
        for (int j = 0; j < 4; ++j) {
            int r = rb + kb * 4 + j;
            if (r < NN) swf8[(size_t)r * 128 + col] = f2fp8b(acc3[nt][j] + bias);
        }
    }
}

// ---------------- edge kernel: agg[n] = mean_e relu(SW[src_e] + EAW[e]) ----------------
// 1 node/wave x 8 edge-slots x 8 lanes (16 ch/lane); eaw AND swb fp8 (16B/lane each).
// Pipeline: ssrc 2 iters ahead, data 1 iter ahead. Slot reduction via shfl_xor butterfly
// over lane bits 3-5 (no LDS, no bank conflicts).

__global__ __launch_bounds__(256) void k_edge(
    const int* __restrict__ rowptr, const int* __restrict__ ssrc,
    const unsigned char* __restrict__ eaw, const unsigned char* __restrict__ swf8,
    u16* __restrict__ aggb) {
    const int wv = threadIdx.x >> 6, l = threadIdx.x & 63;
    const int slot = l >> 3;          // 0..7
    const int g = l & 7;              // 16-ch group
    const int n = blockIdx.x * 4 + wv;
    if (n >= NN) return;
    const int e0 = rowptr[n], e1 = rowptr[n + 1];
    float acc[16];
#pragma unroll
    for (int c = 0; c < 16; ++c) acc[c] = 0.f;

    int i = e0 + slot;
    uint4 qc = {0, 0, 0, 0}, sac = {0, 0, 0, 0};
    if (i < e1) {
        int sc = ssrc[i];
        qc = *(const uint4*)(eaw + (size_t)i * 128 + g * 16);
        sac = *(const uint4*)(swf8 + (size_t)sc * 128 + g * 16);
    }
    int inext = i + 8;
    int snext = (inext < e1) ? ssrc[inext] : 0;
    while (i < e1) {
        // prefetch iteration i+8 (data) and i+16 (index)
        int i2 = inext + 8;
        int s2 = (i2 < e1) ? ssrc[i2] : 0;
        uint4 qn = {0, 0, 0, 0}, san = {0, 0, 0, 0};
        if (inext < e1) {
            qn = *(const uint4*)(eaw + (size_t)inext * 128 + g * 16);
            san = *(const uint4*)(swf8 + (size_t)snext * 128 + g * 16);
        }
        // compute on current staged data
        float ef[16], sw[16];
        fp8x4f(qc.x, ef[0], ef[1], ef[2], ef[3]);
        fp8x4f(qc.y, ef[4], ef[5], ef[6], ef[7]);
        fp8x4f(qc.z, ef[8], ef[9], ef[10], ef[11]);
        fp8x4f(qc.w, ef[12], ef[13], ef[14], ef[15]);
        fp8x4f(sac.x, sw[0], sw[1], sw[2], sw[3]);
        fp8x4f(sac.y, sw[4], sw[5], sw[6], sw[7]);
        fp8x4f(sac.z, sw[8], sw[9], sw[10], sw[11]);
        fp8x4f(sac.w, sw[12], sw[13], sw[14], sw[15]);
#pragma unroll
        for (int c = 0; c < 16; ++c) {
            float m = sw[c] + ef[c];
            acc[c] += m > 0.f ? m : 0.f;
        }
        qc = qn; sac = san;
        i = inext;
        inext = i2;
        snext = s2;
    }
    // butterfly reduction across slots (lane bits 3..5); all lanes end with full sums
#pragma unroll
    for (int c = 0; c < 16; ++c) acc[c] += __shfl_xor(acc[c], 8);
#pragma unroll
    for (int c = 0; c < 16; ++c) acc[c] += __shfl_xor(acc[c], 16);
#pragma unroll
    for (int c = 0; c < 16; ++c) acc[c] += __shfl_xor(acc[c], 32);
    if (slot == 0) {
        int dg = e1 - e0;
        float inv = 1.f / (float)(dg > 0 ? dg : 1);
        uint4 w0, w1;
        w0.x = (u32)f2bf(acc[0] * inv)  | ((u32)f2bf(acc[1] * inv) << 16);
        w0.y = (u32)f2bf(acc[2] * inv)  | ((u32)f2bf(acc[3] * inv) << 16);
        w0.z = (u32)f2bf(acc[4] * inv)  | ((u32)f2bf(acc[5] * inv) << 16);
        w0.w = (u32)f2bf(acc[6] * inv)  | ((u32)f2bf(acc[7] * inv) << 16);
        w1.x = (u32)f2bf(acc[8] * inv)  | ((u32)f2bf(acc[9] * inv) << 16);
        w1.y = (u32)f2bf(acc[10] * inv) | ((u32)f2bf(acc[11] * inv) << 16);
        w1.z = (u32)f2bf(acc[12] * inv) | ((u32)f2bf(acc[13] * inv) << 16);
        w1.w = (u32)f2bf(acc[14] * inv) | ((u32)f2bf(acc[15] * inv) << 16);
        *(uint4*)(aggb + (size_t)n * 128 + g * 16) = w0;
        *(uint4*)(aggb + (size_t)n * 128 + g * 16 + 8) = w1;
    }
}

// ---------------- update kernel (4 waves/block, R=1: 16 rows/wave, bf16 state, fp8 swb out) ----------------
// h=relu([state,agg]@W1+b1); state+=h@W2+b2; swf8=fp8(state@Ws+msg_b)

__global__ __launch_bounds__(256) void k_update(
    const float* __restrict__ up_b1, const float* __restrict__ up_b2,
    const float* __restrict__ msg_b, const u16* __restrict__ packed,
    const u16* __restrict__ aggb, u16* __restrict__ state_h,
    unsigned char* __restrict__ swf8) {
    __shared__ u16 stage[4][2048];
    const int wv = threadIdx.x >> 6, l = threadIdx.x & 63;
    const int lr = l & 15, kb = l >> 4;
    const int rbase = blockIdx.x * 64 + wv * 16;
    const int row = rbase + lr;
    const int rowc = row < NN ? row : NN - 1;

    // GEMM1: K=256 over [state_h, aggb]
    f32x4 acc[8] = {};
#pragma unroll
    for (int ks = 0; ks < 8; ++ks) {
        const u16* abase = (ks < 4)
            ? (state_h + (size_t)rowc * 128 + ks * 32 + kb * 8)
            : (aggb + (size_t)rowc * 128 + (ks - 4) * 32 + kb * 8);
        short8 a = *(const short8*)abase;
        const u16* bp = packed + W1OFF + (size_t)(ks * 512 + l) * 8;
#pragma unroll
        for (int nt = 0; nt < 8; ++nt) {
            short8 b = *(const short8*)(bp + nt * 512);
            acc[nt] = mfma16(a, b, acc[nt]);
        }
    }
    // h = relu(acc + b1) -> stage
#pragma unroll
    for (int nt = 0; nt < 8; ++nt) {
        int col = nt * 16 + lr;
        float b1v = up_b1[col];
#pragma unroll
        for (int j = 0; j < 4; ++j) {
            int rl = kb * 4 + j;
            float v = acc[nt][j] + b1v;
            v = v > 0.f ? v : 0.f;
            int byte = (rl * 256 + col * 2) ^ ((rl & 7) << 4);
            *(u16*)((char*)stage[wv] + byte) = f2bf(v);
        }
    }
    // GEMM2: delta = h @ W2
    f32x4 acc2[8] = {};
#pragma unroll
    for (int ks = 0; ks < 4; ++ks) {
        int byte = (lr * 256 + ks * 64 + kb * 16) ^ ((lr & 7) << 4);
        short8 a = *(const short8*)((char*)stage[wv] + byte);
        const u16* bp = packed + W2OFF + (size_t)(ks * 512 + l) * 8;
#pragma unroll
        for (int nt = 0; nt < 8; ++nt) {
            short8 b = *(const short8*)(bp + nt * 512);
            acc2[nt] = mfma16(a, b, acc2[nt]);
        }
    }
    // state_h += delta + b2 (bf16 master); stage <- state_new [wave-local, in-order]
#pragma unroll
    for (int nt = 0; nt < 8; ++nt) {
        int col = nt * 16 + lr;
        float b2v = up_b2[col];
#pragma unroll
        for (int j = 0; j < 4; ++j) {
            int rl = kb * 4 + j;
            int r = rbase + rl;
            int rc = r < NN ? r : NN - 1;
            float sold = bf2f((u32)state_h[(size_t)rc * 128 + col]);
            float snew = sold + acc2[nt][j] + b2v;
            u16 hb = f2bf(snew);
            if (r < NN) state_h[(size_t)r * 128 + col] = hb;
            int byte = (rl * 256 + col * 2) ^ ((rl & 7) << 4);
            *(u16*)((char*)stage[wv] + byte) = hb;
        }
    }
    // GEMM3: swf8 = fp8(state_new @ Ws + msg_b)
    f32x4 acc3[8] = {};
#pragma unroll
    for (int ks = 0; ks < 4; ++ks) {
        int byte = (lr * 256 + ks * 64 + kb * 16) ^ ((lr & 7) << 4);
        short8 a = *(const short8*)((char*)stage[wv] + byte);
        const u16* bp = packed + WSOFF + (size_t)(ks * 512 + l) * 8;
#pragma unroll
        for (int nt = 0; nt < 8; ++nt) {
            short8 b = *(const short8*)(bp + nt * 512);
            acc3[nt] = mfma16(a, b, acc3[nt]);
        }
    }
#pragma unroll
    for (int nt = 0; nt < 8; ++nt) {
        int col = nt * 16 + lr;
        float bias = msg_b[col];
#pragma unroll
        for (int j = 0; j < 4; ++j) {
            int r = rbase + kb * 4 + j;
            if (r < NN) swf8[(size_t)r * 128 + col] = f2fp8b(acc3[nt][j] + bias);
        }
    }
}

// ---------------- logits: deterministic batched segment mean over sorted batch ----------------

__global__ void k_logits(const u16* __restrict__ state_h, const int* __restrict__ batch,
                         float* __restrict__ out) {
    __shared__ float red[256];
    int b = blockIdx.x, t = threadIdx.x;
    int ch = t & 7, sub = t >> 3;
    int lo = 0, hi = NN;
    while (lo < hi) { int m = (lo + hi) >> 1; if (batch[m] < b) lo = m + 1; else hi = m; }
    int s0 = lo;
    lo = 0; hi = NN;
    while (lo < hi) { int m = (lo + hi) >> 1; if (batch[m] < b + 1) lo = m + 1; else hi = m; }
    int s1 = lo;
    float acc = 0.f;
    for (int n = s0 + sub; n < s1; n += 32)
        acc += bf2f((u32)state_h[(size_t)n * 128 + 120 + ch]);
    red[t] = acc;
    __syncthreads();
    for (int off = 16; off >= 1; off >>= 1) {
        if (sub < off) red[t] += red[t + off * 8];
        __syncthreads();
    }
    if (sub == 0) {
        int c = s1 - s0;
        float cnt = (float)(c > 0 ? c : 1);
        out[b * 8 + ch] = red[ch] / cnt;
    }
}

// ---------------- launch ----------------

extern "C" void kernel_launch(void* const* d_in, const int* in_sizes, int n_in,
                              void* d_out, int out_size, void* d_ws, size_t ws_size,
                              hipStream_t stream) {
    (void)in_sizes; (void)n_in;
    const float* x      = (const float*)d_in[0];
    const int*   eidx   = (const int*)d_in[1];
    const float* eattr  = (const float*)d_in[2];
    const int*   batch  = (const int*)d_in[3];
    const float* enc_w  = (const float*)d_in[4];
    const float* enc_b  = (const float*)d_in[5];
    const float* msg_w  = (const float*)d_in[6];
    const float* msg_b  = (const float*)d_in[7];
    const float* up_w1  = (const float*)d_in[8];
    const float* up_b1  = (const float*)d_in[9];
    const float* up_w2  = (const float*)d_in[10];
    const float* up_b2  = (const float*)d_in[11];
    const int* esrc = eidx;
    const int* edst = eidx + NE;

    char* p = (char*)d_ws;
    size_t off = 0;
    auto carve = [&](size_t bytes) -> char* {
        char* r = p + off;
        off += (bytes + 255) & ~(size_t)255;
        return r;
    };
    u16* state_h   = (u16*)carve((size_t)NN * 128 * 2);
    u16* aggb      = (u16*)carve((size_t)NN * 128 * 2);
    unsigned char* swf8 = (unsigned char*)carve((size_t)NN * 128);
    int* ssrc      = (int*)carve((size_t)NE * 4);
    u16* ea8       = (u16*)carve((size_t)NE * 8 * 2);
    unsigned char* eaw = (unsigned char*)carve((size_t)NE * 128);
    int* rowptr    = (int*)carve((size_t)(NN + 1) * 4);
    int* cursor    = (int*)carve((size_t)NN * 4);
    int* hist      = (int*)carve((size_t)NN * 4);
    int* sexcl     = (int*)carve((size_t)NN * 4);
    int* bsum      = (int*)carve((size_t)256 * 4);
    u16* packed    = (u16*)carve((size_t)PACKN * 2);
    if (off > ws_size) {
        // sentinel: NaN output tells us the workspace was too small
        hipMemsetAsync(d_out, 0xFF, (size_t)out_size * 4, stream);
        return;
    }

    hipMemsetAsync(hist, 0, (size_t)NN * 4, stream);
    k_hist<<<(NE + 255) / 256, 256, 0, stream>>>(edst, hist);
    k_scanA<<<SCAN_B, 256, 0, stream>>>(hist, sexcl, bsum);
    k_scanB<<<1, 256, 0, stream>>>(bsum);
    k_scanC<<<SCAN_B, 256, 0, stream>>>(sexcl, bsum, rowptr, cursor);
    k_scatter<<<(NE + 255) / 256, 256, 0, stream>>>(esrc, edst, eattr, cursor, ssrc, ea8);
    k_eaw<<<EAW_BLOCKS, 256, 0, stream>>>(ea8, msg_w, eaw);
    k_pack<<<(PACKN + 255) / 256, 256, 0, stream>>>(up_w1, up_w2, msg_w, enc_w, packed);
    k_encode<<<(NN + 63) / 64, 256, 0, stream>>>(x, enc_b, msg_b, packed, state_h, swf8);
    for (int t = 0; t < T_STEPS; ++t) {
        k_edge<<<(NN + 3) / 4, 256, 0, stream>>>(rowptr, ssrc, eaw, swf8, aggb);
        k_update<<<(NN + 63) / 64, 256, 0, stream>>>(up_b1, up_b2, msg_b, packed, aggb,
                                                     state_h, swf8);
    }
    k_logits<<<NB, 256, 0, stream>>>(state_h, batch, (float*)d_out);
}

// Round 17
// 1021.625 us; speedup vs baseline: 1.0539x; 1.0539x over previous
//
#include <hip/hip_runtime.h>
#include <hip/hip_bf16.h>

#define NN 50000
#define NE 800000
#define NB 16
#define T_STEPS 12
#define SCAN_B 196  // ceil(NN/256)
#define EAW_BLOCKS 2048

typedef __attribute__((ext_vector_type(8))) short short8;
typedef __attribute__((ext_vector_type(4))) float f32x4;
typedef __attribute__((ext_vector_type(2))) float f32x2;
typedef unsigned short u16;
typedef unsigned int u32;

#if __has_builtin(__builtin_amdgcn_fdot2_f32_bf16)
#define HAS_DOT2_BF16 1
typedef __attribute__((ext_vector_type(2))) __bf16 bf16x2;
__device__ __forceinline__ bf16x2 as_bf16x2(u32 v) {
    union { u32 i; bf16x2 h; } u; u.i = v; return u.h;
}
#else
#define HAS_DOT2_BF16 0
#endif

__device__ __forceinline__ float bf2f(u32 u) {
    union { u32 i; float f; } v; v.i = u << 16; return v.f;
}
__device__ __forceinline__ u16 f2bf(float f) {
    union { float f; u32 i; } v; v.f = f;
    u32 r = v.i + 0x7fffu + ((v.i >> 16) & 1u);
    return (u16)(r >> 16);
}
__device__ __forceinline__ f32x4 mfma16(short8 a, short8 b, f32x4 c) {
    return __builtin_amdgcn_mfma_f32_16x16x32_bf16(a, b, c, 0, 0, 0);
}

// pack 2 floats -> fp8 e4m3 pair in low 16 bits (HW instruction; OCP on gfx950)
__device__ __forceinline__ u32 pk2_fp8(float o0, float o1) {
#if __has_builtin(__builtin_amdgcn_cvt_pk_fp8_f32)
    return (u32)__builtin_amdgcn_cvt_pk_fp8_f32(o0, o1, 0, false);
#else
    u32 a = 0;
    asm("v_cvt_pk_fp8_f32 %0, %1, %2" : "+v"(a) : "v"(o0), "v"(o1));
    return a;
#endif
}
__device__ __forceinline__ u32 pk4_fp8(float o0, float o1, float o2, float o3) {
    return (pk2_fp8(o0, o1) & 0xffffu) | (pk2_fp8(o2, o3) << 16);
}
__device__ __forceinline__ unsigned char f2fp8b(float v) {
    return (unsigned char)(pk2_fp8(v, 0.f) & 0xffu);
}

// decode 4x fp8 e4m3 from u32
__device__ __forceinline__ void fp8x4f(u32 w, float& f0, float& f1, float& f2, float& f3) {
#if __has_builtin(__builtin_amdgcn_cvt_pk_f32_fp8)
    f32x2 r0 = __builtin_amdgcn_cvt_pk_f32_fp8((int)w, false);
    f32x2 r1 = __builtin_amdgcn_cvt_pk_f32_fp8((int)w, true);
    f0 = r0[0]; f1 = r0[1]; f2 = r1[0]; f3 = r1[1];
#else
    f32x2 r0, r1;
    u32 hi = w >> 16;
    asm("v_cvt_pk_f32_fp8 %0, %1" : "=v"(r0) : "v"(w));
    asm("v_cvt_pk_f32_fp8 %0, %1" : "=v"(r1) : "v"(hi));
    f0 = r0[0]; f1 = r0[1]; f2 = r1[0]; f3 = r1[1];
#endif
}

// packed weight layout (bf16): elem(((ks*8+nt)*64+l)*8+j) = W[ks*32+((l>>4))*8+j][nt*16+(l&15)]
#define W1OFF 0
#define W2OFF 32768
#define WSOFF 49152
#define ENCOFF 65536
#define PACKN 73728

// ---------------- setup kernels ----------------

__global__ void k_hist(const int* __restrict__ dst, int* __restrict__ hist) {
    int e = blockIdx.x * 256 + threadIdx.x;
    if (e < NE) atomicAdd(&hist[dst[e]], 1);
}

__global__ void k_scanA(const int* __restrict__ hist, int* __restrict__ excl,
                        int* __restrict__ bsum) {
    __shared__ int sh[256];
    int t = threadIdx.x, b = blockIdx.x;
    int idx = b * 256 + t;
    int v = (idx < NN) ? hist[idx] : 0;
    sh[t] = v;
    __syncthreads();
    for (int off = 1; off < 256; off <<= 1) {
        int add = (t >= off) ? sh[t - off] : 0;
        __syncthreads();
        sh[t] += add;
        __syncthreads();
    }
    if (idx < NN) excl[idx] = sh[t] - v;
    if (t == 255) bsum[b] = sh[255];
}

__global__ void k_scanB(int* __restrict__ bsum) {
    __shared__ int sh[256];
    int t = threadIdx.x;
    int v = (t < SCAN_B) ? bsum[t] : 0;
    sh[t] = v;
    __syncthreads();
    for (int off = 1; off < 256; off <<= 1) {
        int add = (t >= off) ? sh[t - off] : 0;
        __syncthreads();
        sh[t] += add;
        __syncthreads();
    }
    if (t < SCAN_B) bsum[t] = sh[t] - v;  // exclusive
}

__global__ void k_scanC(const int* __restrict__ excl, const int* __restrict__ bsum,
                        int* __restrict__ rowptr, int* __restrict__ cursor) {
    int idx = blockIdx.x * 256 + threadIdx.x;
    if (idx < NN) {
        int r = excl[idx] + bsum[blockIdx.x];
        rowptr[idx] = r;
        cursor[idx] = r;
    }
    if (idx == 0) rowptr[NN] = NE;
}

// scatter (src id + bf16 edge-attr) into CSR order; atomic-latency-bound, stores ~free.
__global__ void k_scatter(const int* __restrict__ src, const int* __restrict__ dst,
                          const float* __restrict__ eattr, int* __restrict__ cursor,
                          int* __restrict__ ssrc, u16* __restrict__ ea8) {
    int e = blockIdx.x * 256 + threadIdx.x;
    if (e >= NE) return;
    int d = dst[e];
    int pos = atomicAdd(&cursor[d], 1);
    ssrc[pos] = src[e];
    const float* ap = eattr + (size_t)e * 8;
    uint4 w;
    w.x = (u32)f2bf(ap[0]) | ((u32)f2bf(ap[1]) << 16);
    w.y = (u32)f2bf(ap[2]) | ((u32)f2bf(ap[3]) << 16);
    w.z = (u32)f2bf(ap[4]) | ((u32)f2bf(ap[5]) << 16);
    w.w = (u32)f2bf(ap[6]) | ((u32)f2bf(ap[7]) << 16);
    *(uint4*)(ea8 + (size_t)pos * 8) = w;
}

// eaw[p][c] = fp8( sum_k ea8[p][k] * msg_w[128+k][c] ) — fully coalesced stream.
// dot2-bf16 path: ea8 words ARE bf16 pairs; weights pre-packed as bf16 pairs (32 VGPR).
__global__ __launch_bounds__(256) void k_eaw(
    const u16* __restrict__ ea8, const float* __restrict__ msg_w,
    unsigned char* __restrict__ eaw) {
    const int tid = threadIdx.x;
    const int hex = tid & 15;   // channel slice [hex*8, hex*8+8)
    const int esub = tid >> 4;  // 0..15
#if HAS_DOT2_BF16
    u32 wp[4][8];
#pragma unroll
    for (int kk = 0; kk < 4; ++kk) {
#pragma unroll
        for (int c = 0; c < 8; ++c) {
            float w0 = msg_w[(size_t)(128 + 2 * kk) * 128 + hex * 8 + c];
            float w1 = msg_w[(size_t)(128 + 2 * kk + 1) * 128 + hex * 8 + c];
            wp[kk][c] = (u32)f2bf(w0) | ((u32)f2bf(w1) << 16);
        }
    }
#else
    float w[8][8];
#pragma unroll
    for (int k = 0; k < 8; ++k) {
        float4 v0 = *(const float4*)(msg_w + (size_t)(128 + k) * 128 + hex * 8);
        float4 v1 = *(const float4*)(msg_w + (size_t)(128 + k) * 128 + hex * 8 + 4);
        w[k][0] = v0.x; w[k][1] = v0.y; w[k][2] = v0.z; w[k][3] = v0.w;
        w[k][4] = v1.x; w[k][5] = v1.y; w[k][6] = v1.z; w[k][7] = v1.w;
    }
#endif
    int p = blockIdx.x * 16 + esub;
    if (p >= NE) return;
    uint4 ev = *(const uint4*)(ea8 + (size_t)p * 8);
    while (true) {
        int pn = p + EAW_BLOCKS * 16;
        bool more = pn < NE;
        uint4 evn;
        if (more) evn = *(const uint4*)(ea8 + (size_t)pn * 8);
        float o[8];
#if HAS_DOT2_BF16
        u32 ep[4] = {ev.x, ev.y, ev.z, ev.w};
#pragma unroll
        for (int c = 0; c < 8; ++c) o[c] = 0.f;
#pragma unroll
        for (int kk = 0; kk < 4; ++kk) {
            bf16x2 ea2 = as_bf16x2(ep[kk]);
#pragma unroll
            for (int c = 0; c < 8; ++c)
                o[c] = __builtin_amdgcn_fdot2_f32_bf16(ea2, as_bf16x2(wp[kk][c]), o[c], false);
        }
#else
        float ef[8];
        ef[0] = bf2f(ev.x & 0xffffu); ef[1] = bf2f(ev.x >> 16);
        ef[2] = bf2f(ev.y & 0xffffu); ef[3] = bf2f(ev.y >> 16);
        ef[4] = bf2f(ev.z & 0xffffu); ef[5] = bf2f(ev.z >> 16);
        ef[6] = bf2f(ev.w & 0xffffu); ef[7] = bf2f(ev.w >> 16);
#pragma unroll
        for (int c = 0; c < 8; ++c) o[c] = ef[0] * w[0][c];
#pragma unroll
        for (int k = 1; k < 8; ++k)
#pragma unroll
            for (int c = 0; c < 8; ++c) o[c] += ef[k] * w[k][c];
#endif
        uint2 q;
        q.x = pk4_fp8(o[0], o[1], o[2], o[3]);
        q.y = pk4_fp8(o[4], o[5], o[6], o[7]);
        *(uint2*)(eaw + (size_t)p * 128 + hex * 8) = q;
        if (!more) break;
        p = pn;
        ev = evn;
    }
}

__global__ void k_pack(const float* __restrict__ up_w1, const float* __restrict__ up_w2,
                       const float* __restrict__ msg_w, const float* __restrict__ enc_w,
                       u16* __restrict__ packed) {
    int idx = blockIdx.x * 256 + threadIdx.x;
    if (idx >= PACKN) return;
    const float* srcp; int local;
    if (idx < W2OFF)        { srcp = up_w1; local = idx; }
    else if (idx < WSOFF)   { srcp = up_w2; local = idx - W2OFF; }
    else if (idx < ENCOFF)  { srcp = msg_w; local = idx - WSOFF; }   // rows 0..127 (state part)
    else                    { srcp = enc_w; local = idx - ENCOFF; }
    int j = local & 7;
    int l = (local >> 3) & 63;
    int ntks = local >> 9;
    int nt = ntks & 7;
    int ks = ntks >> 3;
    int krow = ks * 32 + (l >> 4) * 8 + j;
    int col = nt * 16 + (l & 15);
    packed[idx] = f2bf(srcp[krow * 128 + col]);
}

// ---------------- encoder: state_h = bf16(relu(x@enc_w+enc_b)); swf8 = fp8(state@Ws+msg_b) ----------------

__global__ __launch_bounds__(256) void k_encode(
    const float* __restrict__ x, const float* __restrict__ enc_b,
    const float* __restrict__ msg_b, const u16* __restrict__ packed,
    u16* __restrict__ state_h, unsigned char* __restrict__ swf8) {
    __shared__ u16 stage[4][2048];
    const int wv = threadIdx.x >> 6, l = threadIdx.x & 63;
    const int lr = l & 15, kb = l >> 4;
    const int rb = blockIdx.x * 64 + wv * 16;
    const int row = rb + lr;
    const int rowc = row < NN ? row : NN - 1;

    f32x4 acc[8] = {};
#pragma unroll
    for (int ks = 0; ks < 2; ++ks) {
        const float* ap = x + (size_t)rowc * 64 + ks * 32 + kb * 8;
        float4 a0 = *(const float4*)ap;
        float4 a1 = *(const float4*)(ap + 4);
        short8 a;
        a[0] = (short)f2bf(a0.x); a[1] = (short)f2bf(a0.y);
        a[2] = (short)f2bf(a0.z); a[3] = (short)f2bf(a0.w);
        a[4] = (short)f2bf(a1.x); a[5] = (short)f2bf(a1.y);
        a[6] = (short)f2bf(a1.z); a[7] = (short)f2bf(a1.w);
        const u16* bp = packed + ENCOFF + (size_t)(ks * 512 + l) * 8;
#pragma unroll
        for (int nt = 0; nt < 8; ++nt) {
            short8 b = *(const short8*)(bp + nt * 512);
            acc[nt] = mfma16(a, b, acc[nt]);
        }
    }
#pragma unroll
    for (int nt = 0; nt < 8; ++nt) {
        int col = nt * 16 + lr;
        float bias = enc_b[col];
#pragma unroll
        for (int j = 0; j < 4; ++j) {
            int rl = kb * 4 + j;
            int r = rb + rl;
            float v = acc[nt][j] + bias;
            v = v > 0.f ? v : 0.f;
            u16 h = f2bf(v);
            if (r < NN) state_h[(size_t)r * 128 + col] = h;
            int byte = (rl * 256 + col * 2) ^ ((rl & 7) << 4);
            *(u16*)((char*)stage[wv] + byte) = h;
        }
    }
    f32x4 acc3[8] = {};
#pragma unroll
    for (int ks = 0; ks < 4; ++ks) {
        int byte = (lr * 256 + ks * 64 + kb * 16) ^ ((lr & 7) << 4);
        short8 a = *(const short8*)((char*)stage[wv] + byte);
        const u16* bp = packed + WSOFF + (size_t)(ks * 512 + l) * 8;
#pragma unroll
        for (int nt = 0; nt < 8; ++nt) {
            short8 b = *(const short8*)(bp + nt * 512);
            acc3[nt] = mfma16(a, b, acc3[nt]);
        }
    }
#pragma unroll
    for (int nt = 0; nt < 8; ++nt) {
        int col = nt * 16 + lr;
        float bias = msg_b[col];
#pragma unroll
        for (int j = 0; j < 4; ++j) {
            int r = rb + kb * 4 + j;
            if (r < NN) swf8[(size_t)r * 128 + col] = f2fp8b(acc3[nt][j] + bias);
        }
    }
}

// ---------------- edge kernel: agg[n] = mean_e relu(SW[src_e] + EAW[e]) ----------------
// 1 node/wave x 8 edge-slots x 8 lanes (16 ch/lane); eaw AND swb fp8 (16B/lane each).
// Pipeline: ssrc 2 iters ahead, data 1 iter ahead. Slot reduction via shfl_xor butterfly
// over lane bits 3-5 (no LDS, no bank conflicts).

__global__ __launch_bounds__(256) void k_edge(
    const int* __restrict__ rowptr, const int* __restrict__ ssrc,
    const unsigned char* __restrict__ eaw, const unsigned char* __restrict__ swf8,
    u16* __restrict__ aggb) {
    const int wv = threadIdx.x >> 6, l = threadIdx.x & 63;
    const int slot = l >> 3;          // 0..7
    const int g = l & 7;              // 16-ch group
    const int n = blockIdx.x * 4 + wv;
    if (n >= NN) return;
    const int e0 = rowptr[n], e1 = rowptr[n + 1];
    float acc[16];
#pragma unroll
    for (int c = 0; c < 16; ++c) acc[c] = 0.f;

    int i = e0 + slot;
    uint4 qc = {0, 0, 0, 0}, sac = {0, 0, 0, 0};
    if (i < e1) {
        int sc = ssrc[i];
        qc = *(const uint4*)(eaw + (size_t)i * 128 + g * 16);
        sac = *(const uint4*)(swf8 + (size_t)sc * 128 + g * 16);
    }
    int inext = i + 8;
    int snext = (inext < e1) ? ssrc[inext] : 0;
    while (i < e1) {
        // prefetch iteration i+8 (data) and i+16 (index)
        int i2 = inext + 8;
        int s2 = (i2 < e1) ? ssrc[i2] : 0;
        uint4 qn = {0, 0, 0, 0}, san = {0, 0, 0, 0};
        if (inext < e1) {
            qn = *(const uint4*)(eaw + (size_t)inext * 128 + g * 16);
            san = *(const uint4*)(swf8 + (size_t)snext * 128 + g * 16);
        }
        // compute on current staged data
        float ef[16], sw[16];
        fp8x4f(qc.x, ef[0], ef[1], ef[2], ef[3]);
        fp8x4f(qc.y, ef[4], ef[5], ef[6], ef[7]);
        fp8x4f(qc.z, ef[8], ef[9], ef[10], ef[11]);
        fp8x4f(qc.w, ef[12], ef[13], ef[14], ef[15]);
        fp8x4f(sac.x, sw[0], sw[1], sw[2], sw[3]);
        fp8x4f(sac.y, sw[4], sw[5], sw[6], sw[7]);
        fp8x4f(sac.z, sw[8], sw[9], sw[10], sw[11]);
        fp8x4f(sac.w, sw[12], sw[13], sw[14], sw[15]);
#pragma unroll
        for (int c = 0; c < 16; ++c) {
            float m = sw[c] + ef[c];
            acc[c] += m > 0.f ? m : 0.f;
        }
        qc = qn; sac = san;
        i = inext;
        inext = i2;
        snext = s2;
    }
    // butterfly reduction across slots (lane bits 3..5); all lanes end with full sums
#pragma unroll
    for (int c = 0; c < 16; ++c) acc[c] += __shfl_xor(acc[c], 8);
#pragma unroll
    for (int c = 0; c < 16; ++c) acc[c] += __shfl_xor(acc[c], 16);
#pragma unroll
    for (int c = 0; c < 16; ++c) acc[c] += __shfl_xor(acc[c], 32);
    if (slot == 0) {
        int dg = e1 - e0;
        float inv = 1.f / (float)(dg > 0 ? dg : 1);
        uint4 w0, w1;
        w0.x = (u32)f2bf(acc[0] * inv)  | ((u32)f2bf(acc[1] * inv) << 16);
        w0.y = (u32)f2bf(acc[2] * inv)  | ((u32)f2bf(acc[3] * inv) << 16);
        w0.z = (u32)f2bf(acc[4] * inv)  | ((u32)f2bf(acc[5] * inv) << 16);
        w0.w = (u32)f2bf(acc[6] * inv)  | ((u32)f2bf(acc[7] * inv) << 16);
        w1.x = (u32)f2bf(acc[8] * inv)  | ((u32)f2bf(acc[9] * inv) << 16);
        w1.y = (u32)f2bf(acc[10] * inv) | ((u32)f2bf(acc[11] * inv) << 16);
        w1.z = (u32)f2bf(acc[12] * inv) | ((u32)f2bf(acc[13] * inv) << 16);
        w1.w = (u32)f2bf(acc[14] * inv) | ((u32)f2bf(acc[15] * inv) << 16);
        *(uint4*)(aggb + (size_t)n * 128 + g * 16) = w0;
        *(uint4*)(aggb + (size_t)n * 128 + g * 16 + 8) = w1;
    }
}

// ---------------- update kernel (2 waves/block, R=2 row tiles/wave, bf16 state, fp8 swb out) ----------------
// h=relu([state,agg]@W1+b1); state+=h@W2+b2; swf8=fp8(state@Ws+msg_b)

__global__ __launch_bounds__(128) void k_update(
    const float* __restrict__ up_b1, const float* __restrict__ up_b2,
    const float* __restrict__ msg_b, const u16* __restrict__ packed,
    const u16* __restrict__ aggb, u16* __restrict__ state_h,
    unsigned char* __restrict__ swf8) {
    __shared__ u16 stage[2][2][2048];
    const int wv = threadIdx.x >> 6, l = threadIdx.x & 63;
    const int lr = l & 15, kb = l >> 4;
    const int rbase = blockIdx.x * 64 + wv * 32;

    // GEMM1: K=256 over [state_h, aggb], 2 row tiles
    f32x4 acc[2][8] = {};
#pragma unroll
    for (int ks = 0; ks < 8; ++ks) {
        short8 a[2];
#pragma unroll
        for (int rt = 0; rt < 2; ++rt) {
            int row = rbase + rt * 16 + lr;
            int rowc = row < NN ? row : NN - 1;
            const u16* abase = (ks < 4)
                ? (state_h + (size_t)rowc * 128 + ks * 32 + kb * 8)
                : (aggb + (size_t)rowc * 128 + (ks - 4) * 32 + kb * 8);
            a[rt] = *(const short8*)abase;
        }
        const u16* bp = packed + W1OFF + (size_t)(ks * 512 + l) * 8;
#pragma unroll
        for (int nt = 0; nt < 8; ++nt) {
            short8 b = *(const short8*)(bp + nt * 512);
            acc[0][nt] = mfma16(a[0], b, acc[0][nt]);
            acc[1][nt] = mfma16(a[1], b, acc[1][nt]);
        }
    }
    // h = relu(acc + b1) -> stage
#pragma unroll
    for (int nt = 0; nt < 8; ++nt) {
        int col = nt * 16 + lr;
        float b1v = up_b1[col];
#pragma unroll
        for (int rt = 0; rt < 2; ++rt) {
#pragma unroll
            for (int j = 0; j < 4; ++j) {
                int rl = kb * 4 + j;
                float v = acc[rt][nt][j] + b1v;
                v = v > 0.f ? v : 0.f;
                int byte = (rl * 256 + col * 2) ^ ((rl & 7) << 4);
                *(u16*)((char*)stage[wv][rt] + byte) = f2bf(v);
            }
        }
    }
    // GEMM2: delta = h @ W2
    f32x4 acc2[2][8] = {};
#pragma unroll
    for (int ks = 0; ks < 4; ++ks) {
        int byte = (lr * 256 + ks * 64 + kb * 16) ^ ((lr & 7) << 4);
        short8 a[2];
        a[0] = *(const short8*)((char*)stage[wv][0] + byte);
        a[1] = *(const short8*)((char*)stage[wv][1] + byte);
        const u16* bp = packed + W2OFF + (size_t)(ks * 512 + l) * 8;
#pragma unroll
        for (int nt = 0; nt < 8; ++nt) {
            short8 b = *(const short8*)(bp + nt * 512);
            acc2[0][nt] = mfma16(a[0], b, acc2[0][nt]);
            acc2[1][nt] = mfma16(a[1], b, acc2[1][nt]);
        }
    }
    // state_h += delta + b2 (bf16 master); stage <- state_new [wave-local, in-order]
#pragma unroll
    for (int rt = 0; rt < 2; ++rt) {
#pragma unroll
        for (int nt = 0; nt < 8; ++nt) {
            int col = nt * 16 + lr;
            float b2v = up_b2[col];
#pragma unroll
            for (int j = 0; j < 4; ++j) {
                int rl = kb * 4 + j;
                int r = rbase + rt * 16 + rl;
                int rc = r < NN ? r : NN - 1;
                float sold = bf2f((u32)state_h[(size_t)rc * 128 + col]);
                float snew = sold + acc2[rt][nt][j] + b2v;
                u16 hb = f2bf(snew);
                if (r < NN) state_h[(size_t)r * 128 + col] = hb;
                int byte = (rl * 256 + col * 2) ^ ((rl & 7) << 4);
                *(u16*)((char*)stage[wv][rt] + byte) = hb;
            }
        }
    }
    // GEMM3: swf8 = fp8(state_new @ Ws + msg_b)
    f32x4 acc3[2][8] = {};
#pragma unroll
    for (int ks = 0; ks < 4; ++ks) {
        int byte = (lr * 256 + ks * 64 + kb * 16) ^ ((lr & 7) << 4);
        short8 a[2];
        a[0] = *(const short8*)((char*)stage[wv][0] + byte);
        a[1] = *(const short8*)((char*)stage[wv][1] + byte);
        const u16* bp = packed + WSOFF + (size_t)(ks * 512 + l) * 8;
#pragma unroll
        for (int nt = 0; nt < 8; ++nt) {
            short8 b = *(const short8*)(bp + nt * 512);
            acc3[0][nt] = mfma16(a[0], b, acc3[0][nt]);
            acc3[1][nt] = mfma16(a[1], b, acc3[1][nt]);
        }
    }
#pragma unroll
    for (int rt = 0; rt < 2; ++rt) {
#pragma unroll
        for (int nt = 0; nt < 8; ++nt) {
            int col = nt * 16 + lr;
            float bias = msg_b[col];
#pragma unroll
            for (int j = 0; j < 4; ++j) {
                int r = rbase + rt * 16 + kb * 4 + j;
                if (r < NN) swf8[(size_t)r * 128 + col] = f2fp8b(acc3[rt][nt][j] + bias);
            }
        }
    }
}

// ---------------- logits: deterministic batched segment mean over sorted batch ----------------

__global__ void k_logits(const u16* __restrict__ state_h, const int* __restrict__ batch,
                         float* __restrict__ out) {
    __shared__ float red[256];
    int b = blockIdx.x, t = threadIdx.x;
    int ch = t & 7, sub = t >> 3;
    int lo = 0, hi = NN;
    while (lo < hi) { int m = (lo + hi) >> 1; if (batch[m] < b) lo = m + 1; else hi = m; }
    int s0 = lo;
    lo = 0; hi = NN;
    while (lo < hi) { int m = (lo + hi) >> 1; if (batch[m] < b + 1) lo = m + 1; else hi = m; }
    int s1 = lo;
    float acc = 0.f;
    for (int n = s0 + sub; n < s1; n += 32)
        acc += bf2f((u32)state_h[(size_t)n * 128 + 120 + ch]);
    red[t] = acc;
    __syncthreads();
    for (int off = 16; off >= 1; off >>= 1) {
        if (sub < off) red[t] += red[t + off * 8];
        __syncthreads();
    }
    if (sub == 0) {
        int c = s1 - s0;
        float cnt = (float)(c > 0 ? c : 1);
        out[b * 8 + ch] = red[ch] / cnt;
    }
}

// ---------------- launch ----------------

extern "C" void kernel_launch(void* const* d_in, const int* in_sizes, int n_in,
                              void* d_out, int out_size, void* d_ws, size_t ws_size,
                              hipStream_t stream) {
    (void)in_sizes; (void)n_in;
    const float* x      = (const float*)d_in[0];
    const int*   eidx   = (const int*)d_in[1];
    const float* eattr  = (const float*)d_in[2];
    const int*   batch  = (const int*)d_in[3];
    const float* enc_w  = (const float*)d_in[4];
    const float* enc_b  = (const float*)d_in[5];
    const float* msg_w  = (const float*)d_in[6];
    const float* msg_b  = (const float*)d_in[7];
    const float* up_w1  = (const float*)d_in[8];
    const float* up_b1  = (const float*)d_in[9];
    const float* up_w2  = (const float*)d_in[10];
    const float* up_b2  = (const float*)d_in[11];
    const int* esrc = eidx;
    const int* edst = eidx + NE;

    char* p = (char*)d_ws;
    size_t off = 0;
    auto carve = [&](size_t bytes) -> char* {
        char* r = p + off;
        off += (bytes + 255) & ~(size_t)255;
        return r;
    };
    u16* state_h   = (u16*)carve((size_t)NN * 128 * 2);
    u16* aggb      = (u16*)carve((size_t)NN * 128 * 2);
    unsigned char* swf8 = (unsigned char*)carve((size_t)NN * 128);
    int* ssrc      = (int*)carve((size_t)NE * 4);
    u16* ea8       = (u16*)carve((size_t)NE * 8 * 2);
    unsigned char* eaw = (unsigned char*)carve((size_t)NE * 128);
    int* rowptr    = (int*)carve((size_t)(NN + 1) * 4);
    int* cursor    = (int*)carve((size_t)NN * 4);
    int* hist      = (int*)carve((size_t)NN * 4);
    int* sexcl     = (int*)carve((size_t)NN * 4);
    int* bsum      = (int*)carve((size_t)256 * 4);
    u16* packed    = (u16*)carve((size_t)PACKN * 2);
    if (off > ws_size) {
        // sentinel: NaN output tells us the workspace was too small
        hipMemsetAsync(d_out, 0xFF, (size_t)out_size * 4, stream);
        return;
    }

    hipMemsetAsync(hist, 0, (size_t)NN * 4, stream);
    k_hist<<<(NE + 255) / 256, 256, 0, stream>>>(edst, hist);
    k_scanA<<<SCAN_B, 256, 0, stream>>>(hist, sexcl, bsum);
    k_scanB<<<1, 256, 0, stream>>>(bsum);
    k_scanC<<<SCAN_B, 256, 0, stream>>>(sexcl, bsum, rowptr, cursor);
    k_scatter<<<(NE + 255) / 256, 256, 0, stream>>>(esrc, edst, eattr, cursor, ssrc, ea8);
    k_eaw<<<EAW_BLOCKS, 256, 0, stream>>>(ea8, msg_w, eaw);
    k_pack<<<(PACKN + 255) / 256, 256, 0, stream>>>(up_w1, up_w2, msg_w, enc_w, packed);
    k_encode<<<(NN + 63) / 64, 256, 0, stream>>>(x, enc_b, msg_b, packed, state_h, swf8);
    for (int t = 0; t < T_STEPS; ++t) {
        k_edge<<<(NN + 3) / 4, 256, 0, stream>>>(rowptr, ssrc, eaw, swf8, aggb);
        k_update<<<(NN + 63) / 64, 128, 0, stream>>>(up_b1, up_b2, msg_b, packed, aggb,
                                                     state_h, swf8);
    }
    k_logits<<<NB, 256, 0, stream>>>(state_h, batch, (float*)d_out);
}